// Round 1
// baseline (133.367 us; speedup 1.0000x reference)
//
#include <hip/hip_runtime.h>

#define HW (512 * 512)
#define NB 16
#define NC 4
// workspace layout (floats): S1[16] @0, S2[16] @16, T[16] @32, I[64] @48, U[64] @112
// counts (uint32) @ float-offset 256

__global__ __launch_bounds__(256) void hist_kernel(const int* __restrict__ tgt,
                                                   unsigned int* __restrict__ counts,
                                                   int n4) {
    int idx = blockIdx.x * blockDim.x + threadIdx.x;
    int stride = gridDim.x * blockDim.x;
    unsigned int c0 = 0, c1 = 0, c2 = 0, c3 = 0;
    for (int i = idx; i < n4; i += stride) {
        int4 t = reinterpret_cast<const int4*>(tgt)[i];
        int a = min(max(t.x, 0), 3);
        int b = min(max(t.y, 0), 3);
        int c = min(max(t.z, 0), 3);
        int d = min(max(t.w, 0), 3);
        c0 += (a == 0) + (b == 0) + (c == 0) + (d == 0);
        c1 += (a == 1) + (b == 1) + (c == 1) + (d == 1);
        c2 += (a == 2) + (b == 2) + (c == 2) + (d == 2);
        c3 += (a == 3) + (b == 3) + (c == 3) + (d == 3);
    }
#pragma unroll
    for (int o = 32; o >= 1; o >>= 1) {
        c0 += __shfl_down(c0, o);
        c1 += __shfl_down(c1, o);
        c2 += __shfl_down(c2, o);
        c3 += __shfl_down(c3, o);
    }
    __shared__ unsigned int s[4][4];  // [wave][bin], 256 threads = 4 waves
    int lane = threadIdx.x & 63, wid = threadIdx.x >> 6;
    if (lane == 0) {
        s[wid][0] = c0; s[wid][1] = c1; s[wid][2] = c2; s[wid][3] = c3;
    }
    __syncthreads();
    if (threadIdx.x < 4) {
        unsigned int tot = s[0][threadIdx.x] + s[1][threadIdx.x] + s[2][threadIdx.x] + s[3][threadIdx.x];
        atomicAdd(&counts[threadIdx.x], tot);
    }
}

__global__ __launch_bounds__(256) void main_kernel(const float* __restrict__ pred,
                                                   const int* __restrict__ tgt,
                                                   const unsigned int* __restrict__ counts,
                                                   float* __restrict__ acc) {
    const int n = blockIdx.y;
    float cw[4];
#pragma unroll
    for (int k = 0; k < 4; k++) cw[k] = 1.0f / ((float)counts[k] + 1e-6f);

    float s1 = 0.f, s2 = 0.f, tsum = 0.f;
    float inter[4] = {0.f, 0.f, 0.f, 0.f};
    float uni[4] = {0.f, 0.f, 0.f, 0.f};

    const int4* t4p = reinterpret_cast<const int4*>(tgt + (size_t)n * HW);
    const float4* p0 = reinterpret_cast<const float4*>(pred + (size_t)n * NC * HW + 0 * (size_t)HW);
    const float4* p1 = reinterpret_cast<const float4*>(pred + (size_t)n * NC * HW + 1 * (size_t)HW);
    const float4* p2 = reinterpret_cast<const float4*>(pred + (size_t)n * NC * HW + 2 * (size_t)HW);
    const float4* p3 = reinterpret_cast<const float4*>(pred + (size_t)n * NC * HW + 3 * (size_t)HW);

    int i0 = blockIdx.x * blockDim.x + threadIdx.x;
    const int stride4 = gridDim.x * blockDim.x;  // 64*256 = 16384 groups of 4 pixels
#pragma unroll
    for (int it = 0; it < (HW / 4) / (64 * 256); ++it) {
        int i = i0 + it * stride4;
        int4 t4 = t4p[i];
        float4 a = p0[i];
        float4 b = p1[i];
        float4 c = p2[i];
        float4 d = p3[i];
        int tt[4] = {t4.x, t4.y, t4.z, t4.w};
        float va[4] = {a.x, a.y, a.z, a.w};
        float vb[4] = {b.x, b.y, b.z, b.w};
        float vc[4] = {c.x, c.y, c.z, c.w};
        float vd[4] = {d.x, d.y, d.z, d.w};
#pragma unroll
        for (int j = 0; j < 4; ++j) {
            int t = min(max(tt[j], 0), 3);
            float w = (t == 0) ? cw[0] : (t == 1) ? cw[1] : (t == 2) ? cw[2] : cw[3];
            float x0 = va[j], x1 = vb[j], x2 = vc[j], x3 = vd[j];
            float m = fmaxf(fmaxf(x0, x1), fmaxf(x2, x3));
            float e = __expf(x0 - m) + __expf(x1 - m) + __expf(x2 - m) + __expf(x3 - m);
            float lse = __logf(e) + m;
            float pt = (t == 0) ? x0 : (t == 1) ? x1 : (t == 2) ? x2 : x3;
            float logp_t = pt - lse;
            float tf = (float)t;
            float tw = tf * w;
            s1 += logp_t * w;
            s2 += w;
            tsum += tw;
            inter[0] += x0 * tw; uni[0] += x0 * w;
            inter[1] += x1 * tw; uni[1] += x1 * w;
            inter[2] += x2 * tw; uni[2] += x2 * w;
            inter[3] += x3 * tw; uni[3] += x3 * w;
        }
    }

    // block reduction of 11 partials
    float vals[11] = {s1, s2, tsum, inter[0], inter[1], inter[2], inter[3],
                      uni[0], uni[1], uni[2], uni[3]};
#pragma unroll
    for (int k = 0; k < 11; k++) {
#pragma unroll
        for (int o = 32; o >= 1; o >>= 1) vals[k] += __shfl_down(vals[k], o);
    }
    __shared__ float sred[4][11];
    int lane = threadIdx.x & 63, wid = threadIdx.x >> 6;
    if (lane == 0) {
#pragma unroll
        for (int k = 0; k < 11; k++) sred[wid][k] = vals[k];
    }
    __syncthreads();
    if (threadIdx.x < 11) {
        int k = threadIdx.x;
        float v = sred[0][k] + sred[1][k] + sred[2][k] + sred[3][k];
        int off = (k == 0) ? (0 + n)
                : (k == 1) ? (16 + n)
                : (k == 2) ? (32 + n)
                : (k < 7)  ? (48 + n * 4 + (k - 3))
                           : (112 + n * 4 + (k - 7));
        atomicAdd(&acc[off], v);
    }
}

__global__ __launch_bounds__(64) void finalize_kernel(const float* __restrict__ acc,
                                                      float* __restrict__ out) {
    int lane = threadIdx.x;
    int n = lane >> 2;
    float T = acc[32 + n];
    float I = acc[48 + lane];
    float U = acc[112 + lane];
    float dice_term = 1.0f - (2.0f * I + 1.0f) / (U + T + 1.0f);
    float wce_term = 0.0f;
    if (lane < 16) wce_term = acc[0 + lane] / acc[16 + lane];
#pragma unroll
    for (int o = 32; o >= 1; o >>= 1) {
        dice_term += __shfl_down(dice_term, o);
        wce_term += __shfl_down(wce_term, o);
    }
    if (lane == 0) out[0] = -(wce_term / 16.0f) + dice_term / 64.0f;
}

extern "C" void kernel_launch(void* const* d_in, const int* in_sizes, int n_in,
                              void* d_out, int out_size, void* d_ws, size_t ws_size,
                              hipStream_t stream) {
    const float* pred = (const float*)d_in[0];
    const int* tgt = (const int*)d_in[1];
    float* out = (float*)d_out;
    float* acc = (float*)d_ws;
    unsigned int* counts = (unsigned int*)d_ws + 256;

    hipMemsetAsync(d_ws, 0, 2048, stream);
    hist_kernel<<<1024, 256, 0, stream>>>(tgt, counts, NB * HW / 4);
    dim3 grid(64, NB);
    main_kernel<<<grid, 256, 0, stream>>>(pred, tgt, counts, acc);
    finalize_kernel<<<1, 64, 0, stream>>>(acc, out);
}

// Round 2
// 114.683 us; speedup vs baseline: 1.1629x; 1.1629x over previous
//
#include <hip/hip_runtime.h>

#define HW (512 * 512)
#define NB 16
#define NC 4
#define HBLK 1024   // hist grid blocks
#define MBX 64      // main blocks per image (grid.x)

// ws layout (no zero-init needed; every slot is written before read):
//   uint32 hp[HBLK][4]        @ byte 0       (16 KB)  per-hist-block class counts
//   float  mp[NB*MBX][11]     @ byte 16384   (44 KB)  per-main-block partials
//     k: 0=S1 (logp_t*w), 1=S2 (w), 2=T (t*w), 3..6=I[c], 7..10=U[c]

__global__ __launch_bounds__(256) void hist_kernel(const int* __restrict__ tgt,
                                                   unsigned int* __restrict__ hp,
                                                   int n4) {
    int idx = blockIdx.x * blockDim.x + threadIdx.x;
    int stride = gridDim.x * blockDim.x;
    unsigned int c0 = 0, c1 = 0, c2 = 0, c3 = 0;
    for (int i = idx; i < n4; i += stride) {
        int4 t = reinterpret_cast<const int4*>(tgt)[i];
        int a = min(max(t.x, 0), 3);
        int b = min(max(t.y, 0), 3);
        int c = min(max(t.z, 0), 3);
        int d = min(max(t.w, 0), 3);
        c0 += (a == 0) + (b == 0) + (c == 0) + (d == 0);
        c1 += (a == 1) + (b == 1) + (c == 1) + (d == 1);
        c2 += (a == 2) + (b == 2) + (c == 2) + (d == 2);
        c3 += (a == 3) + (b == 3) + (c == 3) + (d == 3);
    }
#pragma unroll
    for (int o = 32; o >= 1; o >>= 1) {
        c0 += __shfl_down(c0, o);
        c1 += __shfl_down(c1, o);
        c2 += __shfl_down(c2, o);
        c3 += __shfl_down(c3, o);
    }
    __shared__ unsigned int s[4][4];
    int lane = threadIdx.x & 63, wid = threadIdx.x >> 6;
    if (lane == 0) {
        s[wid][0] = c0; s[wid][1] = c1; s[wid][2] = c2; s[wid][3] = c3;
    }
    __syncthreads();
    if (threadIdx.x < 4) {
        // write (not atomic-add) this block's 4 counts
        hp[blockIdx.x * 4 + threadIdx.x] =
            s[0][threadIdx.x] + s[1][threadIdx.x] + s[2][threadIdx.x] + s[3][threadIdx.x];
    }
}

__global__ __launch_bounds__(256) void main_kernel(const float* __restrict__ pred,
                                                   const int* __restrict__ tgt,
                                                   const unsigned int* __restrict__ hp,
                                                   float* __restrict__ mp) {
    const int n = blockIdx.y;
    const int bx = blockIdx.x;

    // --- reduce hist partials (16 KB, L2-resident) to global counts -> weights
    unsigned int c[4] = {0, 0, 0, 0};
#pragma unroll
    for (int j = 0; j < HBLK / 256; ++j) {
        int b = threadIdx.x + j * 256;
        uint4 r = reinterpret_cast<const uint4*>(hp)[b];
        c[0] += r.x; c[1] += r.y; c[2] += r.z; c[3] += r.w;
    }
#pragma unroll
    for (int o = 32; o >= 1; o >>= 1) {
#pragma unroll
        for (int k = 0; k < 4; k++) c[k] += __shfl_down(c[k], o);
    }
    __shared__ unsigned int sc[4][4];
    {
        int lane = threadIdx.x & 63, wid = threadIdx.x >> 6;
        if (lane == 0) {
#pragma unroll
            for (int k = 0; k < 4; k++) sc[wid][k] = c[k];
        }
    }
    __syncthreads();
    float cw[4];
#pragma unroll
    for (int k = 0; k < 4; k++)
        cw[k] = 1.0f / ((float)(sc[0][k] + sc[1][k] + sc[2][k] + sc[3][k]) + 1e-6f);

    // --- main fused pass
    float s1 = 0.f, s2 = 0.f, tsum = 0.f;
    float inter[4] = {0.f, 0.f, 0.f, 0.f};
    float uni[4] = {0.f, 0.f, 0.f, 0.f};

    const int4* t4p = reinterpret_cast<const int4*>(tgt + (size_t)n * HW);
    const float4* p0 = reinterpret_cast<const float4*>(pred + (size_t)n * NC * HW + 0 * (size_t)HW);
    const float4* p1 = reinterpret_cast<const float4*>(pred + (size_t)n * NC * HW + 1 * (size_t)HW);
    const float4* p2 = reinterpret_cast<const float4*>(pred + (size_t)n * NC * HW + 2 * (size_t)HW);
    const float4* p3 = reinterpret_cast<const float4*>(pred + (size_t)n * NC * HW + 3 * (size_t)HW);

    int i0 = bx * blockDim.x + threadIdx.x;
    const int stride4 = MBX * 256;
#pragma unroll
    for (int it = 0; it < (HW / 4) / (MBX * 256); ++it) {
        int i = i0 + it * stride4;
        int4 t4 = t4p[i];
        float4 a = p0[i];
        float4 b = p1[i];
        float4 cc = p2[i];
        float4 d = p3[i];
        int tt[4] = {t4.x, t4.y, t4.z, t4.w};
        float va[4] = {a.x, a.y, a.z, a.w};
        float vb[4] = {b.x, b.y, b.z, b.w};
        float vc[4] = {cc.x, cc.y, cc.z, cc.w};
        float vd[4] = {d.x, d.y, d.z, d.w};
#pragma unroll
        for (int j = 0; j < 4; ++j) {
            int t = min(max(tt[j], 0), 3);
            float w = (t == 0) ? cw[0] : (t == 1) ? cw[1] : (t == 2) ? cw[2] : cw[3];
            float x0 = va[j], x1 = vb[j], x2 = vc[j], x3 = vd[j];
            float m = fmaxf(fmaxf(x0, x1), fmaxf(x2, x3));
            float e = __expf(x0 - m) + __expf(x1 - m) + __expf(x2 - m) + __expf(x3 - m);
            float lse = __logf(e) + m;
            float pt = (t == 0) ? x0 : (t == 1) ? x1 : (t == 2) ? x2 : x3;
            float logp_t = pt - lse;
            float tw = (float)t * w;
            s1 += logp_t * w;
            s2 += w;
            tsum += tw;
            inter[0] += x0 * tw; uni[0] += x0 * w;
            inter[1] += x1 * tw; uni[1] += x1 * w;
            inter[2] += x2 * tw; uni[2] += x2 * w;
            inter[3] += x3 * tw; uni[3] += x3 * w;
        }
    }

    float vals[11] = {s1, s2, tsum, inter[0], inter[1], inter[2], inter[3],
                      uni[0], uni[1], uni[2], uni[3]};
#pragma unroll
    for (int k = 0; k < 11; k++) {
#pragma unroll
        for (int o = 32; o >= 1; o >>= 1) vals[k] += __shfl_down(vals[k], o);
    }
    __shared__ float sred[4][11];
    int lane = threadIdx.x & 63, wid = threadIdx.x >> 6;
    if (lane == 0) {
#pragma unroll
        for (int k = 0; k < 11; k++) sred[wid][k] = vals[k];
    }
    __syncthreads();
    if (threadIdx.x < 11) {
        int k = threadIdx.x;
        // write (not atomic-add) this block's 11 partials
        mp[(n * MBX + bx) * 11 + k] = sred[0][k] + sred[1][k] + sred[2][k] + sred[3][k];
    }
}

__global__ __launch_bounds__(256) void finalize_kernel(const float* __restrict__ mp,
                                                       float* __restrict__ out) {
    __shared__ float red[NB][11];
    int t = threadIdx.x;
    if (t < NB * 11) {
        int n = t / 11, k = t % 11;
        float s = 0.f;
#pragma unroll 8
        for (int bx = 0; bx < MBX; ++bx) s += mp[(n * MBX + bx) * 11 + k];
        red[n][k] = s;
    }
    __syncthreads();
    if (t < 64) {
        int n = t >> 2, cc = t & 3;
        float T = red[n][2];
        float I = red[n][3 + cc];
        float U = red[n][7 + cc];
        float dice_term = 1.0f - (2.0f * I + 1.0f) / (U + T + 1.0f);
        float wce_term = (t < 16) ? (red[t][0] / red[t][1]) : 0.0f;
#pragma unroll
        for (int o = 32; o >= 1; o >>= 1) {
            dice_term += __shfl_down(dice_term, o);
            wce_term += __shfl_down(wce_term, o);
        }
        if (t == 0) out[0] = -(wce_term / 16.0f) + dice_term / 64.0f;
    }
}

extern "C" void kernel_launch(void* const* d_in, const int* in_sizes, int n_in,
                              void* d_out, int out_size, void* d_ws, size_t ws_size,
                              hipStream_t stream) {
    const float* pred = (const float*)d_in[0];
    const int* tgt = (const int*)d_in[1];
    float* out = (float*)d_out;
    unsigned int* hp = (unsigned int*)d_ws;                       // 16 KB
    float* mp = (float*)((char*)d_ws + HBLK * 4 * sizeof(unsigned int));  // 44 KB

    hist_kernel<<<HBLK, 256, 0, stream>>>(tgt, hp, NB * HW / 4);
    dim3 grid(MBX, NB);
    main_kernel<<<grid, 256, 0, stream>>>(pred, tgt, hp, mp);
    finalize_kernel<<<1, 256, 0, stream>>>(mp, out);
}

// Round 3
// 113.602 us; speedup vs baseline: 1.1740x; 1.0095x over previous
//
#include <hip/hip_runtime.h>

#define HW (512 * 512)
#define NB 16
#define NC 4
#define MBX 64            // main blocks per image (grid.x)
#define NBLK (NB * MBX)   // 1024 total main blocks

// Linear decomposition: all weighted sums are linear in per-class weights cw[k],
// so one weight-free pass suffices:
//   cnt[n][k] = #pixels with t=k          (j = k,      0..3)
//   A[n][k]   = sum_{t=k} logp_k          (j = 4+k,    4..7)
//   B[n][k][c]= sum_{t=k} pred_c          (j = 8+4k+c, 8..23)
// finalize: cw[k] = 1/(sum_n cnt + eps);
//   S1 = sum_k cw*A, S2 = sum_k cw*cnt, T = sum_k k*cw*cnt,
//   I[c] = sum_k k*cw*B[k][c], U[c] = sum_k cw*B[k][c]
//
// ws layout: float mp[24][NBLK]  (96 KB, transposed so finalize reads are
// contiguous). Every slot written before read -> no zero-init needed.

__global__ __launch_bounds__(256) void main_kernel(const float* __restrict__ pred,
                                                   const int* __restrict__ tgt,
                                                   float* __restrict__ mp) {
    const int n = blockIdx.y;
    const int bx = blockIdx.x;

    float cnt[4] = {0.f, 0.f, 0.f, 0.f};
    float A[4] = {0.f, 0.f, 0.f, 0.f};
    float B[4][4];
#pragma unroll
    for (int k = 0; k < 4; k++)
#pragma unroll
        for (int c = 0; c < 4; c++) B[k][c] = 0.f;

    const int4* t4p = reinterpret_cast<const int4*>(tgt + (size_t)n * HW);
    const float4* p0 = reinterpret_cast<const float4*>(pred + (size_t)n * NC * HW + 0 * (size_t)HW);
    const float4* p1 = reinterpret_cast<const float4*>(pred + (size_t)n * NC * HW + 1 * (size_t)HW);
    const float4* p2 = reinterpret_cast<const float4*>(pred + (size_t)n * NC * HW + 2 * (size_t)HW);
    const float4* p3 = reinterpret_cast<const float4*>(pred + (size_t)n * NC * HW + 3 * (size_t)HW);

    int i0 = bx * blockDim.x + threadIdx.x;
    const int stride4 = MBX * 256;
#pragma unroll
    for (int it = 0; it < (HW / 4) / (MBX * 256); ++it) {
        int i = i0 + it * stride4;
        int4 t4 = t4p[i];
        float4 a = p0[i];
        float4 b = p1[i];
        float4 cc = p2[i];
        float4 d = p3[i];
        int tt[4] = {t4.x, t4.y, t4.z, t4.w};
        float va[4] = {a.x, a.y, a.z, a.w};
        float vb[4] = {b.x, b.y, b.z, b.w};
        float vc[4] = {cc.x, cc.y, cc.z, cc.w};
        float vd[4] = {d.x, d.y, d.z, d.w};
#pragma unroll
        for (int j = 0; j < 4; ++j) {
            int t = min(max(tt[j], 0), 3);
            float x0 = va[j], x1 = vb[j], x2 = vc[j], x3 = vd[j];
            float m = fmaxf(fmaxf(x0, x1), fmaxf(x2, x3));
            float e = __expf(x0 - m) + __expf(x1 - m) + __expf(x2 - m) + __expf(x3 - m);
            float lse = __logf(e) + m;
            float pt = (t == 0) ? x0 : (t == 1) ? x1 : (t == 2) ? x2 : x3;
            float logp_t = pt - lse;
#pragma unroll
            for (int k = 0; k < 4; ++k) {
                bool hit = (t == k);
                cnt[k] += hit ? 1.0f : 0.0f;
                A[k] += hit ? logp_t : 0.0f;
                B[k][0] += hit ? x0 : 0.0f;
                B[k][1] += hit ? x1 : 0.0f;
                B[k][2] += hit ? x2 : 0.0f;
                B[k][3] += hit ? x3 : 0.0f;
            }
        }
    }

    // block reduction of 24 partials
    float vals[24];
#pragma unroll
    for (int k = 0; k < 4; k++) {
        vals[k] = cnt[k];
        vals[4 + k] = A[k];
#pragma unroll
        for (int c = 0; c < 4; c++) vals[8 + 4 * k + c] = B[k][c];
    }
#pragma unroll
    for (int k = 0; k < 24; k++) {
#pragma unroll
        for (int o = 32; o >= 1; o >>= 1) vals[k] += __shfl_down(vals[k], o);
    }
    __shared__ float sred[4][24];
    int lane = threadIdx.x & 63, wid = threadIdx.x >> 6;
    if (lane == 0) {
#pragma unroll
        for (int k = 0; k < 24; k++) sred[wid][k] = vals[k];
    }
    __syncthreads();
    if (threadIdx.x < 24) {
        int k = threadIdx.x;
        mp[k * NBLK + n * MBX + bx] =
            sred[0][k] + sred[1][k] + sred[2][k] + sred[3][k];
    }
}

__global__ __launch_bounds__(384) void finalize_kernel(const float* __restrict__ mp,
                                                       float* __restrict__ out) {
    __shared__ float red[NB][24];
    __shared__ float cw_s[4];
    int t = threadIdx.x;
    {   // t in [0,384): n = t/24, j = t%24 ; sum 64 contiguous floats
        int n = t / 24, j = t % 24;
        const float4* src = reinterpret_cast<const float4*>(mp + j * NBLK + n * MBX);
        float4 s4 = {0.f, 0.f, 0.f, 0.f};
#pragma unroll
        for (int q = 0; q < MBX / 4; ++q) {
            float4 v = src[q];
            s4.x += v.x; s4.y += v.y; s4.z += v.z; s4.w += v.w;
        }
        red[n][j] = (s4.x + s4.y) + (s4.z + s4.w);
    }
    __syncthreads();
    if (t < 4) {
        float g = 0.f;
#pragma unroll
        for (int n = 0; n < NB; n++) g += red[n][t];
        cw_s[t] = 1.0f / (g + 1e-6f);
    }
    __syncthreads();
    if (t < 64) {
        int n = t >> 2, c = t & 3;
        float cw0 = cw_s[0], cw1 = cw_s[1], cw2 = cw_s[2], cw3 = cw_s[3];
        float T = 1.f * cw1 * red[n][1] + 2.f * cw2 * red[n][2] + 3.f * cw3 * red[n][3];
        float I = 1.f * cw1 * red[n][8 + 4 + c] + 2.f * cw2 * red[n][8 + 8 + c] +
                  3.f * cw3 * red[n][8 + 12 + c];
        float U = cw0 * red[n][8 + 0 + c] + cw1 * red[n][8 + 4 + c] +
                  cw2 * red[n][8 + 8 + c] + cw3 * red[n][8 + 12 + c];
        float dice_term = 1.0f - (2.0f * I + 1.0f) / (U + T + 1.0f);
        float wce_term = 0.0f;
        if (t < 16) {
            float S1 = cw0 * red[t][4] + cw1 * red[t][5] + cw2 * red[t][6] + cw3 * red[t][7];
            float S2 = cw0 * red[t][0] + cw1 * red[t][1] + cw2 * red[t][2] + cw3 * red[t][3];
            wce_term = S1 / S2;
        }
#pragma unroll
        for (int o = 32; o >= 1; o >>= 1) {
            dice_term += __shfl_down(dice_term, o);
            wce_term += __shfl_down(wce_term, o);
        }
        if (t == 0) out[0] = -(wce_term / 16.0f) + dice_term / 64.0f;
    }
}

extern "C" void kernel_launch(void* const* d_in, const int* in_sizes, int n_in,
                              void* d_out, int out_size, void* d_ws, size_t ws_size,
                              hipStream_t stream) {
    const float* pred = (const float*)d_in[0];
    const int* tgt = (const int*)d_in[1];
    float* out = (float*)d_out;
    float* mp = (float*)d_ws;  // 24 * 1024 floats = 96 KB

    dim3 grid(MBX, NB);
    main_kernel<<<grid, 256, 0, stream>>>(pred, tgt, mp);
    finalize_kernel<<<1, 384, 0, stream>>>(mp, out);
}